// Round 23
// baseline (235.650 us; speedup 1.0000x reference)
//
#include <hip/hip_runtime.h>
#include <hip/hip_bf16.h>
#include <math.h>

// InternImage DCNv3 block forward — round 23.
// r22: 210us; sampler fixed by 8px blocks (2x occupancy).  New leader
// gemm_ln2_mlp 55us, grid-limited (784 blk = 3/CU, MfmaUtil 5.5%) — same
// disease.  r23: gemm_ln2_mlp -> 8px/block (1568 blk ~6/CU).  MFMA rows 8-15
// wasted (row-independent, clamped reads, guarded stores) — free at 5.5% util.
// ws: B0 (xn->blended), B1 (xp), B3 (x1) bf16 | packed bf16 weights.

#define BATCH 4
#define HH 56
#define WW 56
#define CC 192
#define NPIX (BATCH * HH * WW)   // 12544
#define XS_STR 200               // 192+8 bf16 row stride
#define H1S 776                  // 768+8
#define OFS 193
#define MLS 97

typedef __hip_bfloat16 bf16;
typedef __attribute__((ext_vector_type(8))) short short8;
typedef __attribute__((ext_vector_type(4))) float float4v;

__device__ __forceinline__ float gelu_exact(float x) {
    return 0.5f * x * (1.f + erff(x * 0.70710678118654752f));
}
__device__ __forceinline__ bf16 f2b(float f) { return __float2bfloat16(f); }
__device__ __forceinline__ float b2f(bf16 h) { return __bfloat162float(h); }
__device__ __forceinline__ float4 ldb4(const bf16* p) {
    const ushort4 u = *(const ushort4*)p;
    float4 r;
    r.x = __uint_as_float((unsigned)u.x << 16);
    r.y = __uint_as_float((unsigned)u.y << 16);
    r.z = __uint_as_float((unsigned)u.z << 16);
    r.w = __uint_as_float((unsigned)u.w << 16);
    return r;
}
__device__ __forceinline__ void stb4(bf16* p, float4 v) {
    ushort4 u;
    bf16 h;
    h = f2b(v.x); u.x = *(unsigned short*)&h;
    h = f2b(v.y); u.y = *(unsigned short*)&h;
    h = f2b(v.z); u.z = *(unsigned short*)&h;
    h = f2b(v.w); u.w = *(unsigned short*)&h;
    *(ushort4*)p = u;
}

// ---- weight prep: pack to MFMA fragment order ------------------------------
__global__ __launch_bounds__(256) void prep_w_k(const float* __restrict__ inpw,
        const float* __restrict__ offw, const float* __restrict__ maskw,
        const float* __restrict__ outpw, const float* __restrict__ fc1w,
        const float* __restrict__ fc2w, bf16* __restrict__ wsB)
{
    const int i = blockIdx.x * 256 + threadIdx.x;
    bf16* inpP = wsB;
    bf16* omP  = wsB + 36864;
    bf16* outP = wsB + 92160;
    bf16* fc1P = wsB + 129024;
    bf16* fc2P = wsB + 276480;
    const int j   = i & 7;
    const int l   = (i >> 3) & 63;
    const int n15 = l & 15, q = l >> 4;
    const int grp = i >> 9;
    if (i < 36864) {
        const int t = grp / 6, c = grp - t * 6;
        const int n = 16 * t + n15, k = 32 * c + 8 * q + j;
        inpP[i] = f2b(inpw[(size_t)k * 192 + n]);
        outP[i] = f2b(outpw[(size_t)k * 192 + n]);
    }
    if (i < 55296) {
        const int t = grp / 6, c = grp - t * 6;
        const int n = 16 * t + n15, k = 32 * c + 8 * q + j;
        omP[i] = (n < 192) ? f2b(offw[(size_t)k * 192 + n])
                           : f2b(maskw[(size_t)k * 96 + (n - 192)]);
    }
    if (i < 147456) {
        const int t1 = grp / 6, c1 = grp - t1 * 6;
        const int n1 = 16 * t1 + n15, k1 = 32 * c1 + 8 * q + j;
        fc1P[i] = f2b(fc1w[(size_t)k1 * 768 + n1]);
        const int t2 = grp / 24, c2 = grp - t2 * 24;
        const int n2 = 16 * t2 + n15, k2 = 32 * c2 + 8 * q + j;
        fc2P[i] = f2b(fc2w[(size_t)k2 * 192 + n2]);
    }
}

// ==== FUSED: LN(x, norm1) + in_proj MFMA.  Writes xn (bf16) and xp (bf16) ====
__global__ __launch_bounds__(256) void ln_gemm16_k(const float* __restrict__ x,
        const float* __restrict__ n1w, const float* __restrict__ n1b,
        const bf16* __restrict__ wP, const float* __restrict__ bias,
        bf16* __restrict__ xn_out, bf16* __restrict__ xp_out)
{
    __shared__ __align__(16) bf16 xs[16 * XS_STR];
    const int tid = threadIdx.x;
    const int w   = tid >> 6;
    const int l   = tid & 63;
    const int n15 = l & 15;
    const int q   = l >> 4;
    const int p0  = blockIdx.x * 16;

    #pragma unroll
    for (int rr = 0; rr < 4; rr++) {
        const int lr = 4 * w + rr;
        const size_t base = (size_t)(p0 + lr) * CC;
        float v[3];
        #pragma unroll
        for (int i = 0; i < 3; i++) v[i] = x[base + l + 64 * i];
        float s = v[0] + v[1] + v[2];
        float qq = v[0]*v[0] + v[1]*v[1] + v[2]*v[2];
        #pragma unroll
        for (int off = 32; off > 0; off >>= 1) {
            s  += __shfl_xor(s, off, 64);
            qq += __shfl_xor(qq, off, 64);
        }
        const float mu  = s * (1.f / CC);
        const float var = qq * (1.f / CC) - mu * mu;
        const float rs  = rsqrtf(var + 1e-5f);
        #pragma unroll
        for (int i = 0; i < 3; i++) {
            const int c = l + 64 * i;
            const bf16 h = f2b((v[i] - mu) * rs * n1w[c] + n1b[c]);
            xs[lr * XS_STR + c] = h;
            xn_out[base + c] = h;
        }
    }
    __syncthreads();

    short8 aF[6];
    #pragma unroll
    for (int c = 0; c < 6; c++)
        aF[c] = *(const short8*)&xs[n15 * XS_STR + c * 32 + q * 8];

    #pragma unroll
    for (int t = 0; t < 3; t++) {
        const int tile = 3 * w + t;
        float4v acc = (float4v){0.f, 0.f, 0.f, 0.f};
        #pragma unroll
        for (int c = 0; c < 6; c++) {
            const short8 bF = *(const short8*)&wP[(size_t)((tile * 6 + c) * 64 + l) * 8];
            acc = __builtin_amdgcn_mfma_f32_16x16x32_bf16(aF[c], bF, acc, 0, 0, 0);
        }
        const int n0 = 16 * tile;
        const float bb = bias[n0 + n15];
        #pragma unroll
        for (int r = 0; r < 4; r++)
            xp_out[(size_t)(p0 + 4 * q + r) * 192 + n0 + n15] = f2b(acc[r] + bb);
    }
}

// ------- dwconv 3x3 (SAME) + LN(1e-6) + GELU: bf16 in/out, XCD-swizzled ------
__global__ __launch_bounds__(256) void dwconv_ln_gelu_k(
        const bf16* __restrict__ xn, const float* __restrict__ dww,
        const float* __restrict__ dwb, const float* __restrict__ lnw,
        const float* __restrict__ lnb, bf16* __restrict__ x1)
{
    __shared__ float cv[4][192];
    const int bid  = (blockIdx.x & 7) * (NPIX / 32) + (blockIdx.x >> 3);
    const int t    = threadIdx.x;
    const int ws   = t >> 6;
    const int l    = t & 63;
    const int pix  = bid * 4 + ws;
    const int bimg = pix / (HH * WW);
    const int hw   = pix - bimg * HH * WW;
    const int h    = hw / WW;
    const int wx   = hw - h * WW;

    if (l < 48) {
        const int c0 = l * 4;
        float4 acc = *(const float4*)&dwb[c0];
        #pragma unroll
        for (int ky = 0; ky < 3; ky++) {
            const int yy = h + ky - 1;
            if (yy < 0 || yy >= HH) continue;
            #pragma unroll
            for (int kx = 0; kx < 3; kx++) {
                const int xx = wx + kx - 1;
                if (xx < 0 || xx >= WW) continue;
                const float4 a = ldb4(&xn[((size_t)(bimg * HH + yy) * WW + xx) * CC + c0]);
                const float4 ww = *(const float4*)&dww[(ky * 3 + kx) * CC + c0];
                acc.x += a.x * ww.x; acc.y += a.y * ww.y;
                acc.z += a.z * ww.z; acc.w += a.w * ww.w;
            }
        }
        *(float4*)&cv[ws][c0] = acc;
    }
    __syncthreads();

    float v[3];
    #pragma unroll
    for (int i = 0; i < 3; i++) v[i] = cv[ws][l + 64 * i];
    float s = v[0] + v[1] + v[2];
    float q = v[0]*v[0] + v[1]*v[1] + v[2]*v[2];
    #pragma unroll
    for (int off = 32; off > 0; off >>= 1) {
        s += __shfl_xor(s, off, 64);
        q += __shfl_xor(q, off, 64);
    }
    const float mu  = s * (1.f / CC);
    const float var = q * (1.f / CC) - mu * mu;
    const float rs  = rsqrtf(var + 1e-6f);
    #pragma unroll
    for (int i = 0; i < 3; i++) {
        const int c = l + 64 * i;
        x1[(size_t)pix * CC + c] = f2b(gelu_exact((v[i] - mu) * rs * lnw[c] + lnb[c]));
    }
}

// ==== FUSED: off+mask MFMA (LDS) + softmax + bilinear + cfs.  8 px/block. ====
__global__ __launch_bounds__(256) void offmask_sample_k(
        const bf16* __restrict__ xp, const bf16* __restrict__ x1g,
        const bf16* __restrict__ omP, const float* __restrict__ offb,
        const float* __restrict__ maskb, const float* __restrict__ cfsw,
        const float* __restrict__ cfsb, bf16* __restrict__ outb)
{
    __shared__ __align__(16) bf16 xs[8 * XS_STR];
    __shared__ float offs_l[8][OFS];
    __shared__ float mls_l[8][MLS];

    const int tid = threadIdx.x;
    const int w   = tid >> 6;
    const int l   = tid & 63;
    const int n15 = l & 15;
    const int q   = l >> 4;
    const int bid = (blockIdx.x & 7) * (NPIX / 64) + (blockIdx.x >> 3);
    const int p0  = bid * 8;

    for (int i = tid; i < 8 * 24; i += 256) {
        const int px = i / 24, c8 = i - px * 24;
        *(short8*)&xs[px * XS_STR + c8 * 8] = *(const short8*)&x1g[(size_t)(p0 + px) * 192 + c8 * 8];
    }
    __syncthreads();

    {
        short8 aF[6];
        #pragma unroll
        for (int c = 0; c < 6; c++)
            aF[c] = (n15 < 8)
                  ? *(const short8*)&xs[n15 * XS_STR + c * 32 + q * 8]
                  : (short8){0, 0, 0, 0, 0, 0, 0, 0};

        for (int t = w; t < 18; t += 4) {
            float4v acc = (float4v){0.f, 0.f, 0.f, 0.f};
            #pragma unroll
            for (int c = 0; c < 6; c++) {
                const short8 bF = *(const short8*)&omP[(size_t)((t * 6 + c) * 64 + l) * 8];
                acc = __builtin_amdgcn_mfma_f32_16x16x32_bf16(aF[c], bF, acc, 0, 0, 0);
            }
            if (q < 2) {
                const int n0 = 16 * t;
                if (t < 12) {
                    const float bb = offb[n0 + n15];
                    #pragma unroll
                    for (int r = 0; r < 4; r++)
                        offs_l[4 * q + r][n0 + n15] = acc[r] + bb;
                } else {
                    const int m0 = n0 - 192;
                    const float bb = maskb[m0 + n15];
                    #pragma unroll
                    for (int r = 0; r < 4; r++)
                        mls_l[4 * q + r][m0 + n15] = acc[r] + bb;
                }
            }
        }
    }
    __syncthreads();

    #pragma unroll
    for (int it = 0; it < 2; it++) {
        const int id = tid + 256 * it;
        if (id >= 384) break;
        const int px  = id / 48;
        const int s2  = id - px * 48;
        const int g   = s2 >> 2;
        const int c4  = s2 & 3;
        const int ch0 = g * 16 + c4 * 4;
        const int pix = p0 + px;
        const int bimg = pix / (HH * WW);
        const int hw   = pix - bimg * HH * WW;
        const int h    = hw / WW;
        const int wxp  = hw - h * WW;

        float lg[8];
        float mx = -1e30f;
        #pragma unroll
        for (int k = 0; k < 8; k++) { lg[k] = mls_l[px][g * 8 + k]; mx = fmaxf(mx, lg[k]); }
        float se = 0.f;
        #pragma unroll
        for (int k = 0; k < 8; k++) { lg[k] = expf(lg[k] - mx); se += lg[k]; }
        const float inv = 1.f / se;

        const int GX[8] = {-1, -1, -1, 0, 0, 1, 1, 1};
        const int GY[8] = {-1, 0, 1, -1, 1, -1, 0, 1};
        const size_t imgbase = (size_t)bimg * HH * WW * CC;

        float4 acc = {0.f, 0.f, 0.f, 0.f};
        #pragma unroll 2
        for (int k = 0; k < 8; k++) {
            const float px_ = (float)wxp + (float)GX[k] + offs_l[px][g * 16 + 2 * k];
            const float py_ = (float)h   + (float)GY[k] + offs_l[px][g * 16 + 2 * k + 1];
            const float fx = floorf(px_), fy = floorf(py_);
            const float wxf = px_ - fx, wyf = py_ - fy;
            const int x0 = (int)fx, y0 = (int)fy;
            float4 v00 = {0,0,0,0}, v01 = {0,0,0,0}, v10 = {0,0,0,0}, v11 = {0,0,0,0};
            if (y0 >= 0 && y0 < HH) {
                if (x0 >= 0 && x0 < WW)
                    v00 = ldb4(&xp[imgbase + (size_t)(y0 * WW + x0) * CC + ch0]);
                if (x0 + 1 >= 0 && x0 + 1 < WW)
                    v01 = ldb4(&xp[imgbase + (size_t)(y0 * WW + x0 + 1) * CC + ch0]);
            }
            if (y0 + 1 >= 0 && y0 + 1 < HH) {
                if (x0 >= 0 && x0 < WW)
                    v10 = ldb4(&xp[imgbase + (size_t)((y0 + 1) * WW + x0) * CC + ch0]);
                if (x0 + 1 >= 0 && x0 + 1 < WW)
                    v11 = ldb4(&xp[imgbase + (size_t)((y0 + 1) * WW + x0 + 1) * CC + ch0]);
            }
            const float w00 = (1.f - wyf) * (1.f - wxf), w01 = (1.f - wyf) * wxf;
            const float w10 = wyf * (1.f - wxf),         w11 = wyf * wxf;
            const float mk = lg[k] * inv;
            acc.x += mk * (w00 * v00.x + w01 * v01.x + w10 * v10.x + w11 * v11.x);
            acc.y += mk * (w00 * v00.y + w01 * v01.y + w10 * v10.y + w11 * v11.y);
            acc.z += mk * (w00 * v00.z + w01 * v01.z + w10 * v10.z + w11 * v11.z);
            acc.w += mk * (w00 * v00.w + w01 * v01.w + w10 * v10.w + w11 * v11.w);
        }

        float part = 0.f;
        #pragma unroll
        for (int j = 0; j < 48; j++)
            part += b2f(xs[px * XS_STR + 4 * j + c4]) * cfsw[(size_t)g * CC + 4 * j + c4];
        part += __shfl_xor(part, 1, 64);
        part += __shfl_xor(part, 2, 64);
        const float cf = 1.f / (1.f + expf(-(part + cfsb[g])));

        const float4 xpc = ldb4(&xp[(size_t)pix * CC + ch0]);
        float4 o;
        o.x = acc.x * (1.f - cf) + xpc.x * cf;
        o.y = acc.y * (1.f - cf) + xpc.y * cf;
        o.z = acc.z * (1.f - cf) + xpc.z * cf;
        o.w = acc.w * (1.f - cf) + xpc.w * cf;
        stb4(&outb[(size_t)pix * CC + ch0], o);
    }
}

// ==== FUSED: out_proj + x2(regs) + xn2(LDS) + fc1+GELU + fc2 + LN + res ======
// 8 px/block, 1568 blocks.  MFMA rows 8-15 wasted; reads clamped (n15&7),
// global loads/stores + LDS partial writes guarded (q < 2).
__global__ __launch_bounds__(256) void gemm_ln2_mlp_k(const bf16* __restrict__ A,
        const bf16* __restrict__ wP, const float* __restrict__ bias,
        const float* __restrict__ x,
        const float* __restrict__ r1w, const float* __restrict__ r1b,
        const float* __restrict__ n2w, const float* __restrict__ n2b,
        const bf16* __restrict__ fc1P, const float* __restrict__ fc1b,
        const bf16* __restrict__ fc2P, const float* __restrict__ fc2b,
        const float* __restrict__ r2w, const float* __restrict__ r2b,
        float* __restrict__ out)
{
    __shared__ __align__(16) bf16 xs[8 * XS_STR];    //  3.2 KB
    __shared__ __align__(16) bf16 h1[8 * H1S];       // 12.4 KB
    __shared__ float ps[4][8], pq[4][8], ps2[4][8], pq2[4][8];

    const int tid = threadIdx.x;
    const int w   = tid >> 6;
    const int l   = tid & 63;
    const int n15 = l & 15;
    const int n7  = n15 & 7;        // clamped row index for A-frag reads
    const int q   = l >> 4;
    const bool act = (q < 2);       // lanes owning valid rows 0..7
    const int p0  = blockIdx.x * 8;

    for (int i = tid; i < 8 * 24; i += 256) {
        const int px = i / 24, c8 = i - px * 24;
        *(short8*)&xs[px * XS_STR + c8 * 8] = *(const short8*)&A[(size_t)(p0 + px) * 192 + c8 * 8];
    }
    __syncthreads();

    // ---- phase A: out_proj MFMA ----
    short8 aF[6];
    #pragma unroll
    for (int c = 0; c < 6; c++)
        aF[c] = *(const short8*)&xs[n7 * XS_STR + c * 32 + q * 8];

    float4v acc[3];
    #pragma unroll
    for (int t = 0; t < 3; t++) {
        const int tile = 3 * w + t;
        acc[t] = (float4v){0.f, 0.f, 0.f, 0.f};
        #pragma unroll
        for (int c = 0; c < 6; c++) {
            const short8 bF = *(const short8*)&wP[(size_t)((tile * 6 + c) * 64 + l) * 8];
            acc[t] = __builtin_amdgcn_mfma_f32_16x16x32_bf16(aF[c], bF, acc[t], 0, 0, 0);
        }
        const float bb = bias[16 * tile + n15];
        #pragma unroll
        for (int r = 0; r < 4; r++) acc[t][r] += bb;
    }

    #pragma unroll
    for (int r = 0; r < 4; r++) {
        float sp = acc[0][r] + acc[1][r] + acc[2][r];
        float qp = acc[0][r]*acc[0][r] + acc[1][r]*acc[1][r] + acc[2][r]*acc[2][r];
        #pragma unroll
        for (int o = 1; o < 16; o <<= 1) {
            sp += __shfl_xor(sp, o, 64);
            qp += __shfl_xor(qp, o, 64);
        }
        if (n15 == 0 && act) { ps[w][4 * q + r] = sp; pq[w][4 * q + r] = qp; }
    }
    __syncthreads();

    // x2 (fp32, regs; valid rows only) + LN2 partials + xn2 -> xs
    float x2v[3][4];
    #pragma unroll
    for (int r = 0; r < 4; r++) {
        if (act) {
            const int row = 4 * q + r;
            const float s  = ps[0][row] + ps[1][row] + ps[2][row] + ps[3][row];
            const float qq = pq[0][row] + pq[1][row] + pq[2][row] + pq[3][row];
            const float mu  = s * (1.f / CC);
            const float var = qq * (1.f / CC) - mu * mu;
            const float rs  = rsqrtf(var + 1e-5f);
            const size_t grow = p0 + row;
            #pragma unroll
            for (int t = 0; t < 3; t++) {
                const int col = 48 * w + 16 * t + n15;
                x2v[t][r] = x[grow * CC + col] + (acc[t][r] - mu) * rs * r1w[col] + r1b[col];
            }
        } else {
            #pragma unroll
            for (int t = 0; t < 3; t++) x2v[t][r] = 0.f;
        }
    }
    #pragma unroll
    for (int r = 0; r < 4; r++) {
        float sp = x2v[0][r] + x2v[1][r] + x2v[2][r];
        float qp = x2v[0][r]*x2v[0][r] + x2v[1][r]*x2v[1][r] + x2v[2][r]*x2v[2][r];
        #pragma unroll
        for (int o = 1; o < 16; o <<= 1) {
            sp += __shfl_xor(sp, o, 64);
            qp += __shfl_xor(qp, o, 64);
        }
        if (n15 == 0 && act) { ps2[w][4 * q + r] = sp; pq2[w][4 * q + r] = qp; }
    }
    __syncthreads();            // also orders xs overwrite vs aF reads

    #pragma unroll
    for (int r = 0; r < 4; r++) {
        if (act) {
            const int row = 4 * q + r;
            const float s  = ps2[0][row] + ps2[1][row] + ps2[2][row] + ps2[3][row];
            const float qq = pq2[0][row] + pq2[1][row] + pq2[2][row] + pq2[3][row];
            const float mu  = s * (1.f / CC);
            const float var = qq * (1.f / CC) - mu * mu;
            const float rs  = rsqrtf(var + 1e-5f);
            #pragma unroll
            for (int t = 0; t < 3; t++) {
                const int col = 48 * w + 16 * t + n15;
                xs[row * XS_STR + col] = f2b((x2v[t][r] - mu) * rs * n2w[col] + n2b[col]);
            }
        }
    }
    __syncthreads();

    // ---- phase B: fc1 + GELU -> h1 (rows 0..7) ----
    short8 aF2[6];
    #pragma unroll
    for (int c = 0; c < 6; c++)
        aF2[c] = *(const short8*)&xs[n7 * XS_STR + c * 32 + q * 8];

    #pragma unroll
    for (int t1 = 0; t1 < 12; t1++) {
        const int tile = 12 * w + t1;
        float4v a1 = (float4v){0.f, 0.f, 0.f, 0.f};
        #pragma unroll
        for (int c = 0; c < 6; c++) {
            const short8 bF = *(const short8*)&fc1P[(size_t)((tile * 6 + c) * 64 + l) * 8];
            a1 = __builtin_amdgcn_mfma_f32_16x16x32_bf16(aF2[c], bF, a1, 0, 0, 0);
        }
        if (act) {
            const int n0 = 16 * tile;
            const float bb = fc1b[n0 + n15];
            #pragma unroll
            for (int r = 0; r < 4; r++)
                h1[(4 * q + r) * H1S + n0 + n15] = f2b(gelu_exact(a1[r] + bb));
        }
    }
    __syncthreads();

    // ---- phase C: fc2 + LN(rpn2) + residual ----
    float4v acc2[3];
    #pragma unroll
    for (int t = 0; t < 3; t++) acc2[t] = (float4v){0.f, 0.f, 0.f, 0.f};
    #pragma unroll 4
    for (int kc = 0; kc < 24; kc++) {
        const short8 a2 = *(const short8*)&h1[n7 * H1S + kc * 32 + q * 8];
        #pragma unroll
        for (int t = 0; t < 3; t++) {
            const int tile = 3 * w + t;
            const short8 bF = *(const short8*)&fc2P[(size_t)((tile * 24 + kc) * 64 + l) * 8];
            acc2[t] = __builtin_amdgcn_mfma_f32_16x16x32_bf16(a2, bF, acc2[t], 0, 0, 0);
        }
    }
    #pragma unroll
    for (int t = 0; t < 3; t++) {
        const float bb = fc2b[48 * w + 16 * t + n15];
        #pragma unroll
        for (int r = 0; r < 4; r++) acc2[t][r] += bb;
    }

    #pragma unroll
    for (int r = 0; r < 4; r++) {
        float sp = acc2[0][r] + acc2[1][r] + acc2[2][r];
        float qp = acc2[0][r]*acc2[0][r] + acc2[1][r]*acc2[1][r] + acc2[2][r]*acc2[2][r];
        #pragma unroll
        for (int o = 1; o < 16; o <<= 1) {
            sp += __shfl_xor(sp, o, 64);
            qp += __shfl_xor(qp, o, 64);
        }
        if (n15 == 0 && act) { ps[w][4 * q + r] = sp; pq[w][4 * q + r] = qp; }
    }
    __syncthreads();

    #pragma unroll
    for (int r = 0; r < 4; r++) {
        if (act) {
            const int row = 4 * q + r;
            const float s  = ps[0][row] + ps[1][row] + ps[2][row] + ps[3][row];
            const float qq = pq[0][row] + pq[1][row] + pq[2][row] + pq[3][row];
            const float mu  = s * (1.f / CC);
            const float var = qq * (1.f / CC) - mu * mu;
            const float rs  = rsqrtf(var + 1e-5f);
            const size_t grow = p0 + row;
            #pragma unroll
            for (int t = 0; t < 3; t++) {
                const int col = 48 * w + 16 * t + n15;
                out[grow * CC + col] = x2v[t][r]
                                     + (acc2[t][r] - mu) * rs * r2w[col] + r2b[col];
            }
        }
    }
}

extern "C" void kernel_launch(void* const* d_in, const int* in_sizes, int n_in,
                              void* d_out, int out_size, void* d_ws, size_t ws_size,
                              hipStream_t stream) {
    const float* x      = (const float*)d_in[0];
    const float* n1w    = (const float*)d_in[1];
    const float* n1b    = (const float*)d_in[2];
    const float* n2w    = (const float*)d_in[3];
    const float* n2b    = (const float*)d_in[4];
    const float* rpn1w  = (const float*)d_in[5];
    const float* rpn1b  = (const float*)d_in[6];
    const float* rpn2w  = (const float*)d_in[7];
    const float* rpn2b  = (const float*)d_in[8];
    const float* inpw   = (const float*)d_in[9];
    const float* inpb   = (const float*)d_in[10];
    const float* dww    = (const float*)d_in[11];
    const float* dwb    = (const float*)d_in[12];
    const float* dwlnw  = (const float*)d_in[13];
    const float* dwlnb  = (const float*)d_in[14];
    const float* offw   = (const float*)d_in[15];
    const float* offb   = (const float*)d_in[16];
    const float* maskw  = (const float*)d_in[17];
    const float* maskb  = (const float*)d_in[18];
    const float* cfsw   = (const float*)d_in[19];
    const float* cfsb   = (const float*)d_in[20];
    const float* outpw  = (const float*)d_in[21];
    const float* outpb  = (const float*)d_in[22];
    const float* fc1w   = (const float*)d_in[23];
    const float* fc1b   = (const float*)d_in[24];
    const float* fc2w   = (const float*)d_in[25];
    const float* fc2b   = (const float*)d_in[26];

    const int N = NPIX;                       // 12544
    const size_t NP = (size_t)N * CC;
    bf16* B0  = (bf16*)d_ws;                  // xn -> blended
    bf16* B1  = B0 + NP;                      // xp
    bf16* B3  = B1 + NP;                      // x1
    bf16* wsB = B3 + NP;                      // packed bf16 weights
    const bf16* inpP = wsB;
    const bf16* omP  = wsB + 36864;
    const bf16* outP = wsB + 92160;
    const bf16* fc1P = wsB + 129024;
    const bf16* fc2P = wsB + 276480;

    const int lnG = N / 4;     // 3136
    const int g16 = N / 16;    // 784
    const int g8  = N / 8;     // 1568

    // 0. weight prep (bf16, fragment-packed)
    prep_w_k<<<576, 256, 0, stream>>>(inpw, offw, maskw, outpw, fc1w, fc2w, wsB);
    // 1. FUSED xn = LN(x); xp = xn @ in_proj + b   -> B0, B1
    ln_gemm16_k<<<g16, 256, 0, stream>>>(x, n1w, n1b, inpP, inpb, B0, B1);
    // 2. x1 = gelu(LN(dwconv(xn), 1e-6))           -> B3
    dwconv_ln_gelu_k<<<lnG, 256, 0, stream>>>(B0, dww, dwb, dwlnw, dwlnb, B3);
    // 3. FUSED off/mask GEMM + sampling (8px blocks) -> B0
    offmask_sample_k<<<g8, 256, 0, stream>>>(B1, B3, omP, offb, maskb,
                                             cfsw, cfsb, B0);
    // 4. FUSED out_proj+LN+LN+fc1+gelu+fc2+LN+res (8px blocks) -> d_out
    gemm_ln2_mlp_k<<<g8, 256, 0, stream>>>(B0, outP, outpb, x, rpn1w, rpn1b,
                                           n2w, n2b, fc1P, fc1b, fc2P, fc2b,
                                           rpn2w, rpn2b, (float*)d_out);
}

// Round 24
// 208.728 us; speedup vs baseline: 1.1290x; 1.1290x over previous
//
#include <hip/hip_runtime.h>
#include <hip/hip_bf16.h>
#include <math.h>

// InternImage DCNv3 block forward — round 24: REVERT to r22 config (best: 209.8us).
// r23 post-mortem: 8px MLP blocks doubled per-block weight streaming (590KB x
// 1568 blocks ~ 925MB L2) -> 55->87us despite higher occupancy.  MLP kernel is
// pinched between weight reuse (bigger blocks) and occupancy (smaller); 16px is
// the measured sweet spot (r15: 32px regressed, r23: 8px regressed).
// Config: sampler 8px (r22 win), MLP 16px (r22 win), 5 launches, bf16
// intermediates, fragment-packed weights, XCD swizzles.
// ws: B0 (xn->blended), B1 (xp), B3 (x1) bf16 | packed bf16 weights.

#define BATCH 4
#define HH 56
#define WW 56
#define CC 192
#define NPIX (BATCH * HH * WW)   // 12544
#define XS_STR 200               // 192+8 bf16 row stride
#define H1S 776                  // 768+8
#define OFS 193
#define MLS 97

typedef __hip_bfloat16 bf16;
typedef __attribute__((ext_vector_type(8))) short short8;
typedef __attribute__((ext_vector_type(4))) float float4v;

__device__ __forceinline__ float gelu_exact(float x) {
    return 0.5f * x * (1.f + erff(x * 0.70710678118654752f));
}
__device__ __forceinline__ bf16 f2b(float f) { return __float2bfloat16(f); }
__device__ __forceinline__ float b2f(bf16 h) { return __bfloat162float(h); }
__device__ __forceinline__ float4 ldb4(const bf16* p) {
    const ushort4 u = *(const ushort4*)p;
    float4 r;
    r.x = __uint_as_float((unsigned)u.x << 16);
    r.y = __uint_as_float((unsigned)u.y << 16);
    r.z = __uint_as_float((unsigned)u.z << 16);
    r.w = __uint_as_float((unsigned)u.w << 16);
    return r;
}
__device__ __forceinline__ void stb4(bf16* p, float4 v) {
    ushort4 u;
    bf16 h;
    h = f2b(v.x); u.x = *(unsigned short*)&h;
    h = f2b(v.y); u.y = *(unsigned short*)&h;
    h = f2b(v.z); u.z = *(unsigned short*)&h;
    h = f2b(v.w); u.w = *(unsigned short*)&h;
    *(ushort4*)p = u;
}

// ---- weight prep: pack to MFMA fragment order ------------------------------
__global__ __launch_bounds__(256) void prep_w_k(const float* __restrict__ inpw,
        const float* __restrict__ offw, const float* __restrict__ maskw,
        const float* __restrict__ outpw, const float* __restrict__ fc1w,
        const float* __restrict__ fc2w, bf16* __restrict__ wsB)
{
    const int i = blockIdx.x * 256 + threadIdx.x;
    bf16* inpP = wsB;
    bf16* omP  = wsB + 36864;
    bf16* outP = wsB + 92160;
    bf16* fc1P = wsB + 129024;
    bf16* fc2P = wsB + 276480;
    const int j   = i & 7;
    const int l   = (i >> 3) & 63;
    const int n15 = l & 15, q = l >> 4;
    const int grp = i >> 9;
    if (i < 36864) {
        const int t = grp / 6, c = grp - t * 6;
        const int n = 16 * t + n15, k = 32 * c + 8 * q + j;
        inpP[i] = f2b(inpw[(size_t)k * 192 + n]);
        outP[i] = f2b(outpw[(size_t)k * 192 + n]);
    }
    if (i < 55296) {
        const int t = grp / 6, c = grp - t * 6;
        const int n = 16 * t + n15, k = 32 * c + 8 * q + j;
        omP[i] = (n < 192) ? f2b(offw[(size_t)k * 192 + n])
                           : f2b(maskw[(size_t)k * 96 + (n - 192)]);
    }
    if (i < 147456) {
        const int t1 = grp / 6, c1 = grp - t1 * 6;
        const int n1 = 16 * t1 + n15, k1 = 32 * c1 + 8 * q + j;
        fc1P[i] = f2b(fc1w[(size_t)k1 * 768 + n1]);
        const int t2 = grp / 24, c2 = grp - t2 * 24;
        const int n2 = 16 * t2 + n15, k2 = 32 * c2 + 8 * q + j;
        fc2P[i] = f2b(fc2w[(size_t)k2 * 192 + n2]);
    }
}

// ==== FUSED: LN(x, norm1) + in_proj MFMA.  Writes xn (bf16) and xp (bf16) ====
__global__ __launch_bounds__(256) void ln_gemm16_k(const float* __restrict__ x,
        const float* __restrict__ n1w, const float* __restrict__ n1b,
        const bf16* __restrict__ wP, const float* __restrict__ bias,
        bf16* __restrict__ xn_out, bf16* __restrict__ xp_out)
{
    __shared__ __align__(16) bf16 xs[16 * XS_STR];
    const int tid = threadIdx.x;
    const int w   = tid >> 6;
    const int l   = tid & 63;
    const int n15 = l & 15;
    const int q   = l >> 4;
    const int p0  = blockIdx.x * 16;

    #pragma unroll
    for (int rr = 0; rr < 4; rr++) {
        const int lr = 4 * w + rr;
        const size_t base = (size_t)(p0 + lr) * CC;
        float v[3];
        #pragma unroll
        for (int i = 0; i < 3; i++) v[i] = x[base + l + 64 * i];
        float s = v[0] + v[1] + v[2];
        float qq = v[0]*v[0] + v[1]*v[1] + v[2]*v[2];
        #pragma unroll
        for (int off = 32; off > 0; off >>= 1) {
            s  += __shfl_xor(s, off, 64);
            qq += __shfl_xor(qq, off, 64);
        }
        const float mu  = s * (1.f / CC);
        const float var = qq * (1.f / CC) - mu * mu;
        const float rs  = rsqrtf(var + 1e-5f);
        #pragma unroll
        for (int i = 0; i < 3; i++) {
            const int c = l + 64 * i;
            const bf16 h = f2b((v[i] - mu) * rs * n1w[c] + n1b[c]);
            xs[lr * XS_STR + c] = h;
            xn_out[base + c] = h;
        }
    }
    __syncthreads();

    short8 aF[6];
    #pragma unroll
    for (int c = 0; c < 6; c++)
        aF[c] = *(const short8*)&xs[n15 * XS_STR + c * 32 + q * 8];

    #pragma unroll
    for (int t = 0; t < 3; t++) {
        const int tile = 3 * w + t;
        float4v acc = (float4v){0.f, 0.f, 0.f, 0.f};
        #pragma unroll
        for (int c = 0; c < 6; c++) {
            const short8 bF = *(const short8*)&wP[(size_t)((tile * 6 + c) * 64 + l) * 8];
            acc = __builtin_amdgcn_mfma_f32_16x16x32_bf16(aF[c], bF, acc, 0, 0, 0);
        }
        const int n0 = 16 * tile;
        const float bb = bias[n0 + n15];
        #pragma unroll
        for (int r = 0; r < 4; r++)
            xp_out[(size_t)(p0 + 4 * q + r) * 192 + n0 + n15] = f2b(acc[r] + bb);
    }
}

// ------- dwconv 3x3 (SAME) + LN(1e-6) + GELU: bf16 in/out, XCD-swizzled ------
__global__ __launch_bounds__(256) void dwconv_ln_gelu_k(
        const bf16* __restrict__ xn, const float* __restrict__ dww,
        const float* __restrict__ dwb, const float* __restrict__ lnw,
        const float* __restrict__ lnb, bf16* __restrict__ x1)
{
    __shared__ float cv[4][192];
    const int bid  = (blockIdx.x & 7) * (NPIX / 32) + (blockIdx.x >> 3);
    const int t    = threadIdx.x;
    const int ws   = t >> 6;
    const int l    = t & 63;
    const int pix  = bid * 4 + ws;
    const int bimg = pix / (HH * WW);
    const int hw   = pix - bimg * HH * WW;
    const int h    = hw / WW;
    const int wx   = hw - h * WW;

    if (l < 48) {
        const int c0 = l * 4;
        float4 acc = *(const float4*)&dwb[c0];
        #pragma unroll
        for (int ky = 0; ky < 3; ky++) {
            const int yy = h + ky - 1;
            if (yy < 0 || yy >= HH) continue;
            #pragma unroll
            for (int kx = 0; kx < 3; kx++) {
                const int xx = wx + kx - 1;
                if (xx < 0 || xx >= WW) continue;
                const float4 a = ldb4(&xn[((size_t)(bimg * HH + yy) * WW + xx) * CC + c0]);
                const float4 ww = *(const float4*)&dww[(ky * 3 + kx) * CC + c0];
                acc.x += a.x * ww.x; acc.y += a.y * ww.y;
                acc.z += a.z * ww.z; acc.w += a.w * ww.w;
            }
        }
        *(float4*)&cv[ws][c0] = acc;
    }
    __syncthreads();

    float v[3];
    #pragma unroll
    for (int i = 0; i < 3; i++) v[i] = cv[ws][l + 64 * i];
    float s = v[0] + v[1] + v[2];
    float q = v[0]*v[0] + v[1]*v[1] + v[2]*v[2];
    #pragma unroll
    for (int off = 32; off > 0; off >>= 1) {
        s += __shfl_xor(s, off, 64);
        q += __shfl_xor(q, off, 64);
    }
    const float mu  = s * (1.f / CC);
    const float var = q * (1.f / CC) - mu * mu;
    const float rs  = rsqrtf(var + 1e-6f);
    #pragma unroll
    for (int i = 0; i < 3; i++) {
        const int c = l + 64 * i;
        x1[(size_t)pix * CC + c] = f2b(gelu_exact((v[i] - mu) * rs * lnw[c] + lnb[c]));
    }
}

// ==== FUSED: off+mask MFMA (LDS) + softmax + bilinear + cfs.  8 px/block. ====
__global__ __launch_bounds__(256) void offmask_sample_k(
        const bf16* __restrict__ xp, const bf16* __restrict__ x1g,
        const bf16* __restrict__ omP, const float* __restrict__ offb,
        const float* __restrict__ maskb, const float* __restrict__ cfsw,
        const float* __restrict__ cfsb, bf16* __restrict__ outb)
{
    __shared__ __align__(16) bf16 xs[8 * XS_STR];
    __shared__ float offs_l[8][OFS];
    __shared__ float mls_l[8][MLS];

    const int tid = threadIdx.x;
    const int w   = tid >> 6;
    const int l   = tid & 63;
    const int n15 = l & 15;
    const int q   = l >> 4;
    const int bid = (blockIdx.x & 7) * (NPIX / 64) + (blockIdx.x >> 3);
    const int p0  = bid * 8;

    for (int i = tid; i < 8 * 24; i += 256) {
        const int px = i / 24, c8 = i - px * 24;
        *(short8*)&xs[px * XS_STR + c8 * 8] = *(const short8*)&x1g[(size_t)(p0 + px) * 192 + c8 * 8];
    }
    __syncthreads();

    {
        short8 aF[6];
        #pragma unroll
        for (int c = 0; c < 6; c++)
            aF[c] = (n15 < 8)
                  ? *(const short8*)&xs[n15 * XS_STR + c * 32 + q * 8]
                  : (short8){0, 0, 0, 0, 0, 0, 0, 0};

        for (int t = w; t < 18; t += 4) {
            float4v acc = (float4v){0.f, 0.f, 0.f, 0.f};
            #pragma unroll
            for (int c = 0; c < 6; c++) {
                const short8 bF = *(const short8*)&omP[(size_t)((t * 6 + c) * 64 + l) * 8];
                acc = __builtin_amdgcn_mfma_f32_16x16x32_bf16(aF[c], bF, acc, 0, 0, 0);
            }
            if (q < 2) {
                const int n0 = 16 * t;
                if (t < 12) {
                    const float bb = offb[n0 + n15];
                    #pragma unroll
                    for (int r = 0; r < 4; r++)
                        offs_l[4 * q + r][n0 + n15] = acc[r] + bb;
                } else {
                    const int m0 = n0 - 192;
                    const float bb = maskb[m0 + n15];
                    #pragma unroll
                    for (int r = 0; r < 4; r++)
                        mls_l[4 * q + r][m0 + n15] = acc[r] + bb;
                }
            }
        }
    }
    __syncthreads();

    #pragma unroll
    for (int it = 0; it < 2; it++) {
        const int id = tid + 256 * it;
        if (id >= 384) break;
        const int px  = id / 48;
        const int s2  = id - px * 48;
        const int g   = s2 >> 2;
        const int c4  = s2 & 3;
        const int ch0 = g * 16 + c4 * 4;
        const int pix = p0 + px;
        const int bimg = pix / (HH * WW);
        const int hw   = pix - bimg * HH * WW;
        const int h    = hw / WW;
        const int wxp  = hw - h * WW;

        float lg[8];
        float mx = -1e30f;
        #pragma unroll
        for (int k = 0; k < 8; k++) { lg[k] = mls_l[px][g * 8 + k]; mx = fmaxf(mx, lg[k]); }
        float se = 0.f;
        #pragma unroll
        for (int k = 0; k < 8; k++) { lg[k] = expf(lg[k] - mx); se += lg[k]; }
        const float inv = 1.f / se;

        const int GX[8] = {-1, -1, -1, 0, 0, 1, 1, 1};
        const int GY[8] = {-1, 0, 1, -1, 1, -1, 0, 1};
        const size_t imgbase = (size_t)bimg * HH * WW * CC;

        float4 acc = {0.f, 0.f, 0.f, 0.f};
        #pragma unroll 2
        for (int k = 0; k < 8; k++) {
            const float px_ = (float)wxp + (float)GX[k] + offs_l[px][g * 16 + 2 * k];
            const float py_ = (float)h   + (float)GY[k] + offs_l[px][g * 16 + 2 * k + 1];
            const float fx = floorf(px_), fy = floorf(py_);
            const float wxf = px_ - fx, wyf = py_ - fy;
            const int x0 = (int)fx, y0 = (int)fy;
            float4 v00 = {0,0,0,0}, v01 = {0,0,0,0}, v10 = {0,0,0,0}, v11 = {0,0,0,0};
            if (y0 >= 0 && y0 < HH) {
                if (x0 >= 0 && x0 < WW)
                    v00 = ldb4(&xp[imgbase + (size_t)(y0 * WW + x0) * CC + ch0]);
                if (x0 + 1 >= 0 && x0 + 1 < WW)
                    v01 = ldb4(&xp[imgbase + (size_t)(y0 * WW + x0 + 1) * CC + ch0]);
            }
            if (y0 + 1 >= 0 && y0 + 1 < HH) {
                if (x0 >= 0 && x0 < WW)
                    v10 = ldb4(&xp[imgbase + (size_t)((y0 + 1) * WW + x0) * CC + ch0]);
                if (x0 + 1 >= 0 && x0 + 1 < WW)
                    v11 = ldb4(&xp[imgbase + (size_t)((y0 + 1) * WW + x0 + 1) * CC + ch0]);
            }
            const float w00 = (1.f - wyf) * (1.f - wxf), w01 = (1.f - wyf) * wxf;
            const float w10 = wyf * (1.f - wxf),         w11 = wyf * wxf;
            const float mk = lg[k] * inv;
            acc.x += mk * (w00 * v00.x + w01 * v01.x + w10 * v10.x + w11 * v11.x);
            acc.y += mk * (w00 * v00.y + w01 * v01.y + w10 * v10.y + w11 * v11.y);
            acc.z += mk * (w00 * v00.z + w01 * v01.z + w10 * v10.z + w11 * v11.z);
            acc.w += mk * (w00 * v00.w + w01 * v01.w + w10 * v10.w + w11 * v11.w);
        }

        float part = 0.f;
        #pragma unroll
        for (int j = 0; j < 48; j++)
            part += b2f(xs[px * XS_STR + 4 * j + c4]) * cfsw[(size_t)g * CC + 4 * j + c4];
        part += __shfl_xor(part, 1, 64);
        part += __shfl_xor(part, 2, 64);
        const float cf = 1.f / (1.f + expf(-(part + cfsb[g])));

        const float4 xpc = ldb4(&xp[(size_t)pix * CC + ch0]);
        float4 o;
        o.x = acc.x * (1.f - cf) + xpc.x * cf;
        o.y = acc.y * (1.f - cf) + xpc.y * cf;
        o.z = acc.z * (1.f - cf) + xpc.z * cf;
        o.w = acc.w * (1.f - cf) + xpc.w * cf;
        stb4(&outb[(size_t)pix * CC + ch0], o);
    }
}

// ==== FUSED: out_proj MFMA + x2(regs) + xn2(LDS) + fc1+GELU + fc2 + LN + res =
// 16 px/block (measured sweet spot: weight reuse vs occupancy).
__global__ __launch_bounds__(256) void gemm_ln2_mlp_k(const bf16* __restrict__ A,
        const bf16* __restrict__ wP, const float* __restrict__ bias,
        const float* __restrict__ x,
        const float* __restrict__ r1w, const float* __restrict__ r1b,
        const float* __restrict__ n2w, const float* __restrict__ n2b,
        const bf16* __restrict__ fc1P, const float* __restrict__ fc1b,
        const bf16* __restrict__ fc2P, const float* __restrict__ fc2b,
        const float* __restrict__ r2w, const float* __restrict__ r2b,
        float* __restrict__ out)
{
    __shared__ __align__(16) bf16 xs[16 * XS_STR];
    __shared__ __align__(16) bf16 h1[16 * H1S];
    __shared__ float ps[4][16], pq[4][16], ps2[4][16], pq2[4][16];

    const int tid = threadIdx.x;
    const int w   = tid >> 6;
    const int l   = tid & 63;
    const int n15 = l & 15;
    const int q   = l >> 4;
    const int p0  = blockIdx.x * 16;

    for (int i = tid; i < 16 * 24; i += 256) {
        const int px = i / 24, c8 = i - px * 24;
        *(short8*)&xs[px * XS_STR + c8 * 8] = *(const short8*)&A[(size_t)(p0 + px) * 192 + c8 * 8];
    }
    __syncthreads();

    {
        short8 aF[6];
        #pragma unroll
        for (int c = 0; c < 6; c++)
            aF[c] = *(const short8*)&xs[n15 * XS_STR + c * 32 + q * 8];

        float4v acc[3];
        #pragma unroll
        for (int t = 0; t < 3; t++) {
            const int tile = 3 * w + t;
            acc[t] = (float4v){0.f, 0.f, 0.f, 0.f};
            #pragma unroll
            for (int c = 0; c < 6; c++) {
                const short8 bF = *(const short8*)&wP[(size_t)((tile * 6 + c) * 64 + l) * 8];
                acc[t] = __builtin_amdgcn_mfma_f32_16x16x32_bf16(aF[c], bF, acc[t], 0, 0, 0);
            }
            const float bb = bias[16 * tile + n15];
            #pragma unroll
            for (int r = 0; r < 4; r++) acc[t][r] += bb;
        }

        #pragma unroll
        for (int r = 0; r < 4; r++) {
            float sp = acc[0][r] + acc[1][r] + acc[2][r];
            float qp = acc[0][r]*acc[0][r] + acc[1][r]*acc[1][r] + acc[2][r]*acc[2][r];
            #pragma unroll
            for (int o = 1; o < 16; o <<= 1) {
                sp += __shfl_xor(sp, o, 64);
                qp += __shfl_xor(qp, o, 64);
            }
            if (n15 == 0) { ps[w][4 * q + r] = sp; pq[w][4 * q + r] = qp; }
        }
        __syncthreads();

        float x2v[3][4];
        #pragma unroll
        for (int r = 0; r < 4; r++) {
            const int row = 4 * q + r;
            const float s  = ps[0][row] + ps[1][row] + ps[2][row] + ps[3][row];
            const float qq = pq[0][row] + pq[1][row] + pq[2][row] + pq[3][row];
            const float mu  = s * (1.f / CC);
            const float var = qq * (1.f / CC) - mu * mu;
            const float rs  = rsqrtf(var + 1e-5f);
            const size_t grow = p0 + row;
            #pragma unroll
            for (int t = 0; t < 3; t++) {
                const int col = 48 * w + 16 * t + n15;
                x2v[t][r] = x[grow * CC + col] + (acc[t][r] - mu) * rs * r1w[col] + r1b[col];
            }
        }
        #pragma unroll
        for (int r = 0; r < 4; r++) {
            float sp = x2v[0][r] + x2v[1][r] + x2v[2][r];
            float qp = x2v[0][r]*x2v[0][r] + x2v[1][r]*x2v[1][r] + x2v[2][r]*x2v[2][r];
            #pragma unroll
            for (int o = 1; o < 16; o <<= 1) {
                sp += __shfl_xor(sp, o, 64);
                qp += __shfl_xor(qp, o, 64);
            }
            if (n15 == 0) { ps2[w][4 * q + r] = sp; pq2[w][4 * q + r] = qp; }
        }
        __syncthreads();

        #pragma unroll
        for (int r = 0; r < 4; r++) {
            const int row = 4 * q + r;
            const float s  = ps2[0][row] + ps2[1][row] + ps2[2][row] + ps2[3][row];
            const float qq = pq2[0][row] + pq2[1][row] + pq2[2][row] + pq2[3][row];
            const float mu  = s * (1.f / CC);
            const float var = qq * (1.f / CC) - mu * mu;
            const float rs  = rsqrtf(var + 1e-5f);
            #pragma unroll
            for (int t = 0; t < 3; t++) {
                const int col = 48 * w + 16 * t + n15;
                xs[row * XS_STR + col] = f2b((x2v[t][r] - mu) * rs * n2w[col] + n2b[col]);
            }
        }
        __syncthreads();

        short8 aF2[6];
        #pragma unroll
        for (int c = 0; c < 6; c++)
            aF2[c] = *(const short8*)&xs[n15 * XS_STR + c * 32 + q * 8];

        #pragma unroll
        for (int t1 = 0; t1 < 12; t1++) {
            const int tile = 12 * w + t1;
            float4v a1 = (float4v){0.f, 0.f, 0.f, 0.f};
            #pragma unroll
            for (int c = 0; c < 6; c++) {
                const short8 bF = *(const short8*)&fc1P[(size_t)((tile * 6 + c) * 64 + l) * 8];
                a1 = __builtin_amdgcn_mfma_f32_16x16x32_bf16(aF2[c], bF, a1, 0, 0, 0);
            }
            const int n0 = 16 * tile;
            const float bb = fc1b[n0 + n15];
            #pragma unroll
            for (int r = 0; r < 4; r++)
                h1[(4 * q + r) * H1S + n0 + n15] = f2b(gelu_exact(a1[r] + bb));
        }
        __syncthreads();

        float4v acc2[3];
        #pragma unroll
        for (int t = 0; t < 3; t++) acc2[t] = (float4v){0.f, 0.f, 0.f, 0.f};
        #pragma unroll 4
        for (int kc = 0; kc < 24; kc++) {
            const short8 a2 = *(const short8*)&h1[n15 * H1S + kc * 32 + q * 8];
            #pragma unroll
            for (int t = 0; t < 3; t++) {
                const int tile = 3 * w + t;
                const short8 bF = *(const short8*)&fc2P[(size_t)((tile * 24 + kc) * 64 + l) * 8];
                acc2[t] = __builtin_amdgcn_mfma_f32_16x16x32_bf16(a2, bF, acc2[t], 0, 0, 0);
            }
        }
        #pragma unroll
        for (int t = 0; t < 3; t++) {
            const float bb = fc2b[48 * w + 16 * t + n15];
            #pragma unroll
            for (int r = 0; r < 4; r++) acc2[t][r] += bb;
        }

        #pragma unroll
        for (int r = 0; r < 4; r++) {
            float sp = acc2[0][r] + acc2[1][r] + acc2[2][r];
            float qp = acc2[0][r]*acc2[0][r] + acc2[1][r]*acc2[1][r] + acc2[2][r]*acc2[2][r];
            #pragma unroll
            for (int o = 1; o < 16; o <<= 1) {
                sp += __shfl_xor(sp, o, 64);
                qp += __shfl_xor(qp, o, 64);
            }
            if (n15 == 0) { ps[w][4 * q + r] = sp; pq[w][4 * q + r] = qp; }
        }
        __syncthreads();

        #pragma unroll
        for (int r = 0; r < 4; r++) {
            const int row = 4 * q + r;
            const float s  = ps[0][row] + ps[1][row] + ps[2][row] + ps[3][row];
            const float qq = pq[0][row] + pq[1][row] + pq[2][row] + pq[3][row];
            const float mu  = s * (1.f / CC);
            const float var = qq * (1.f / CC) - mu * mu;
            const float rs  = rsqrtf(var + 1e-5f);
            const size_t grow = p0 + row;
            #pragma unroll
            for (int t = 0; t < 3; t++) {
                const int col = 48 * w + 16 * t + n15;
                out[grow * CC + col] = x2v[t][r]
                                     + (acc2[t][r] - mu) * rs * r2w[col] + r2b[col];
            }
        }
    }
}

extern "C" void kernel_launch(void* const* d_in, const int* in_sizes, int n_in,
                              void* d_out, int out_size, void* d_ws, size_t ws_size,
                              hipStream_t stream) {
    const float* x      = (const float*)d_in[0];
    const float* n1w    = (const float*)d_in[1];
    const float* n1b    = (const float*)d_in[2];
    const float* n2w    = (const float*)d_in[3];
    const float* n2b    = (const float*)d_in[4];
    const float* rpn1w  = (const float*)d_in[5];
    const float* rpn1b  = (const float*)d_in[6];
    const float* rpn2w  = (const float*)d_in[7];
    const float* rpn2b  = (const float*)d_in[8];
    const float* inpw   = (const float*)d_in[9];
    const float* inpb   = (const float*)d_in[10];
    const float* dww    = (const float*)d_in[11];
    const float* dwb    = (const float*)d_in[12];
    const float* dwlnw  = (const float*)d_in[13];
    const float* dwlnb  = (const float*)d_in[14];
    const float* offw   = (const float*)d_in[15];
    const float* offb   = (const float*)d_in[16];
    const float* maskw  = (const float*)d_in[17];
    const float* maskb  = (const float*)d_in[18];
    const float* cfsw   = (const float*)d_in[19];
    const float* cfsb   = (const float*)d_in[20];
    const float* outpw  = (const float*)d_in[21];
    const float* outpb  = (const float*)d_in[22];
    const float* fc1w   = (const float*)d_in[23];
    const float* fc1b   = (const float*)d_in[24];
    const float* fc2w   = (const float*)d_in[25];
    const float* fc2b   = (const float*)d_in[26];

    const int N = NPIX;                       // 12544
    const size_t NP = (size_t)N * CC;
    bf16* B0  = (bf16*)d_ws;                  // xn -> blended
    bf16* B1  = B0 + NP;                      // xp
    bf16* B3  = B1 + NP;                      // x1
    bf16* wsB = B3 + NP;                      // packed bf16 weights
    const bf16* inpP = wsB;
    const bf16* omP  = wsB + 36864;
    const bf16* outP = wsB + 92160;
    const bf16* fc1P = wsB + 129024;
    const bf16* fc2P = wsB + 276480;

    const int lnG = N / 4;     // 3136
    const int g16 = N / 16;    // 784
    const int g8  = N / 8;     // 1568

    // 0. weight prep (bf16, fragment-packed)
    prep_w_k<<<576, 256, 0, stream>>>(inpw, offw, maskw, outpw, fc1w, fc2w, wsB);
    // 1. FUSED xn = LN(x); xp = xn @ in_proj + b   -> B0, B1
    ln_gemm16_k<<<g16, 256, 0, stream>>>(x, n1w, n1b, inpP, inpb, B0, B1);
    // 2. x1 = gelu(LN(dwconv(xn), 1e-6))           -> B3
    dwconv_ln_gelu_k<<<lnG, 256, 0, stream>>>(B0, dww, dwb, dwlnw, dwlnb, B3);
    // 3. FUSED off/mask GEMM + sampling (8px blocks) -> B0
    offmask_sample_k<<<g8, 256, 0, stream>>>(B1, B3, omP, offb, maskb,
                                             cfsw, cfsb, B0);
    // 4. FUSED out_proj+LN+LN+fc1+gelu+fc2+LN+res (16px blocks) -> d_out
    gemm_ln2_mlp_k<<<g16, 256, 0, stream>>>(B0, outP, outpb, x, rpn1w, rpn1b,
                                            n2w, n2b, fc1P, fc1b, fc2P, fc2b,
                                            rpn2w, rpn2b, (float*)d_out);
}